// Round 3
// baseline (557.690 us; speedup 1.0000x reference)
//
#include <hip/hip_runtime.h>
#include <cfloat>

#define BB 32
#define CH 128
#define NT 1024
#define KNN 9

// ---------- sq[b][n] = sum_c x[b][c][n]^2 ; block(0,0) also zeroes BN stats ----------
__global__ __launch_bounds__(256) void k_sq(const float* __restrict__ x,
                                            float* __restrict__ sq,
                                            float* __restrict__ stats) {
  if (blockIdx.x == 0 && blockIdx.y == 0) stats[threadIdx.x] = 0.f;  // 256 floats
  const int b = blockIdx.y;
  const int n = blockIdx.x * 256 + threadIdx.x;
  const float* xb = x + (size_t)b * CH * NT + n;
  float s = 0.f;
#pragma unroll 8
  for (int c = 0; c < CH; ++c) {
    float v = xb[(size_t)c * NT];
    s = fmaf(v, v, s);
  }
  sq[b * NT + n] = s;
}

// ---------- fused pairwise-dist + per-row top-9 + tok emission ----------
// block: 256 threads, owns 64 rows (i) of one batch; sweeps 16 column tiles (j).
// dist = sqrt(max(sq_i + sq_j - 2*dot, 0)) — we compare on the SQRT'd value to
// reproduce the reference's tie structure exactly (rounded sqrt can tie where
// raw d2 differs; lax.top_k then keeps the smaller index, as does our
// ascending-j scan with strictly-smaller-wins insertion). Self (j==i) ~0 kept.
// Also writes tok (B,N,C) from As — the 512 blocks tile all tokens exactly once,
// so a standalone transpose kernel (16 MB extra HBM read) is unnecessary.
__global__ __launch_bounds__(256) void k_dist_topk(const float* __restrict__ x,
                                                   const float* __restrict__ sq,
                                                   int* __restrict__ topk,
                                                   float* __restrict__ tok) {
  __shared__ float As[CH][64];   // full-C stripe of this block's 64 rows
  __shared__ float Bs[32][64];   // c-chunked stripe of current 64 cols
  __shared__ float d2s[64][65];  // +1 pad: serial row scan is conflict-free
  __shared__ float sqi[64];
  __shared__ float sqj[64];
  const int b = blockIdx.y;
  const int i0 = blockIdx.x * 64;
  const int tid = threadIdx.x;
  const int ty = tid >> 4, tx = tid & 15;  // 16x16 threads, 4x4 microtile
  const float* xb = x + (size_t)b * CH * NT;
  const float* sqb = sq + b * NT;

  if (tid < 64) sqi[tid] = sqb[i0 + tid];
#pragma unroll
  for (int k = 0; k < 32; ++k) {  // 8192 elems, coalesced
    int e = tid + k * 256;
    As[e >> 6][e & 63] = xb[(size_t)(e >> 6) * NT + i0 + (e & 63)];
  }

  float val[KNN];
  int idx[KNN];
#pragma unroll
  for (int t = 0; t < KNN; ++t) { val[t] = FLT_MAX; idx[t] = 0x7fffffff; }

  for (int j0 = 0; j0 < NT; j0 += 64) {
    if (tid < 64) sqj[tid] = sqb[j0 + tid];
    float acc[4][4];
#pragma unroll
    for (int r = 0; r < 4; ++r)
#pragma unroll
      for (int q = 0; q < 4; ++q) acc[r][q] = 0.f;

    for (int cc = 0; cc < CH; cc += 32) {
      __syncthreads();  // As/sqj writes visible; Bs reads of prev chunk done
#pragma unroll
      for (int k = 0; k < 8; ++k) {
        int e = tid + k * 256;
        Bs[e >> 6][e & 63] = xb[(size_t)(cc + (e >> 6)) * NT + j0 + (e & 63)];
      }
      __syncthreads();
#pragma unroll
      for (int c = 0; c < 32; ++c) {
        float4 av = *(const float4*)&As[cc + c][ty * 4];  // broadcast, free
        float4 bv = *(const float4*)&Bs[c][tx * 4];       // 2-way, free
        acc[0][0] = fmaf(av.x, bv.x, acc[0][0]);
        acc[0][1] = fmaf(av.x, bv.y, acc[0][1]);
        acc[0][2] = fmaf(av.x, bv.z, acc[0][2]);
        acc[0][3] = fmaf(av.x, bv.w, acc[0][3]);
        acc[1][0] = fmaf(av.y, bv.x, acc[1][0]);
        acc[1][1] = fmaf(av.y, bv.y, acc[1][1]);
        acc[1][2] = fmaf(av.y, bv.z, acc[1][2]);
        acc[1][3] = fmaf(av.y, bv.w, acc[1][3]);
        acc[2][0] = fmaf(av.z, bv.x, acc[2][0]);
        acc[2][1] = fmaf(av.z, bv.y, acc[2][1]);
        acc[2][2] = fmaf(av.z, bv.z, acc[2][2]);
        acc[2][3] = fmaf(av.z, bv.w, acc[2][3]);
        acc[3][0] = fmaf(av.w, bv.x, acc[3][0]);
        acc[3][1] = fmaf(av.w, bv.y, acc[3][1]);
        acc[3][2] = fmaf(av.w, bv.z, acc[3][2]);
        acc[3][3] = fmaf(av.w, bv.w, acc[3][3]);
      }
    }
#pragma unroll
    for (int r = 0; r < 4; ++r) {
      float si = sqi[ty * 4 + r];
#pragma unroll
      for (int q = 0; q < 4; ++q) {
        float v = si + sqj[tx * 4 + q] - 2.0f * acc[r][q];
        d2s[ty * 4 + r][tx * 4 + q] = sqrtf(fmaxf(v, 0.0f));  // compare on dist
      }
    }
    __syncthreads();
    if (tid < 64) {  // wave 0: one row each, register-resident sorted top-9
      for (int j = 0; j < 64; ++j) {
        float v = d2s[tid][j];
        if (v < val[KNN - 1]) {
          bool gt[KNN];
#pragma unroll
          for (int t = 0; t < KNN; ++t) gt[t] = (val[t] > v);
#pragma unroll
          for (int t = KNN - 1; t >= 1; --t)
            if (gt[t - 1]) { val[t] = val[t - 1]; idx[t] = idx[t - 1]; }
#pragma unroll
          for (int t = 0; t < KNN; ++t)
            if (gt[t] && (t == 0 || !gt[t - 1])) { val[t] = v; idx[t] = j0 + j; }
        }
      }
    }
    __syncthreads();  // scan done before next tile overwrites sqj/Bs/d2s
  }
  if (tid < 64) {
    int* tp = topk + ((size_t)b * NT + i0 + tid) * KNN;
#pragma unroll
    for (int t = 0; t < KNN; ++t) tp[t] = idx[t];
  }
  {  // emit tok rows for this block's 64 tokens from As (no extra HBM read).
     // 4-way LDS read conflict (1.58x, epilogue-only); 16B/lane global writes
     // at 128B stride merge to lines in L2 (block's 32KB slice is L2-resident).
    const int n = tid >> 2, q = tid & 3;
    float* tp = tok + ((size_t)b * NT + i0 + n) * CH + q * 32;
#pragma unroll
    for (int i = 0; i < 8; ++i) {
      float4 v;
      v.x = As[q * 32 + 4 * i + 0][n];
      v.y = As[q * 32 + 4 * i + 1][n];
      v.z = As[q * 32 + 4 * i + 2][n];
      v.w = As[q * 32 + 4 * i + 3][n];
      *(float4*)&tp[4 * i] = v;
    }
  }
}

// ---------- gather 9 tokens, mean, GEMM with w^T, +bias, write (B,C,N) ----------
__global__ __launch_bounds__(256) void k_agg_gemm(const float* __restrict__ tok,
                                                  const int* __restrict__ topk,
                                                  const float* __restrict__ w,
                                                  const float* __restrict__ bias,
                                                  float* __restrict__ out) {
  __shared__ float agg_s[64][132];  // pad 4: float4-aligned rows, low conflicts
  __shared__ float w_s[CH][36];     // w chunk transposed [c][d'], pad to 36
  const int b = blockIdx.y;
  const int n0 = blockIdx.x * 64;
  const int tid = threadIdx.x;
  {  // gather+mean: 4 threads per row, 32 channels each
    const int row = tid >> 2, lp = tid & 3;
    const int* tp = topk + ((size_t)b * NT + n0 + row) * KNN;
    float a[32];
#pragma unroll
    for (int i = 0; i < 32; ++i) a[i] = 0.f;
    for (int t = 0; t < KNN; ++t) {
      const float* src = tok + ((size_t)b * NT + tp[t]) * CH + lp * 32;
#pragma unroll
      for (int i = 0; i < 8; ++i) {
        float4 v = *(const float4*)&src[4 * i];
        a[4 * i + 0] += v.x; a[4 * i + 1] += v.y;
        a[4 * i + 2] += v.z; a[4 * i + 3] += v.w;
      }
    }
    const float inv9 = 1.0f / 9.0f;
#pragma unroll
    for (int i = 0; i < 8; ++i) {
      float4 v;
      v.x = a[4 * i + 0] * inv9; v.y = a[4 * i + 1] * inv9;
      v.z = a[4 * i + 2] * inv9; v.w = a[4 * i + 3] * inv9;
      *(float4*)&agg_s[row][lp * 32 + 4 * i] = v;
    }
  }
  const int nn = tid >> 3, dd = tid & 7;  // rows 2nn,2nn+1; d' = dd*4..+3
  for (int d0 = 0; d0 < CH; d0 += 32) {
    __syncthreads();  // agg_s visible (1st iter); w_s reads done (later iters)
#pragma unroll
    for (int k = 0; k < 16; ++k) {
      int e = tid + k * 256;
      int c = e & 127, dl = e >> 7;
      w_s[c][dl] = w[(size_t)(d0 + dl) * CH + c];
    }
    __syncthreads();
    float acc0[4] = {0.f, 0.f, 0.f, 0.f};
    float acc1[4] = {0.f, 0.f, 0.f, 0.f};
    for (int c4 = 0; c4 < 32; ++c4) {
      float4 a0 = *(const float4*)&agg_s[2 * nn][4 * c4];
      float4 a1 = *(const float4*)&agg_s[2 * nn + 1][4 * c4];
      float4 w0 = *(const float4*)&w_s[4 * c4 + 0][dd * 4];
      float4 w1 = *(const float4*)&w_s[4 * c4 + 1][dd * 4];
      float4 w2 = *(const float4*)&w_s[4 * c4 + 2][dd * 4];
      float4 w3 = *(const float4*)&w_s[4 * c4 + 3][dd * 4];
#define GSTEP(AC, WV)                                                          \
  acc0[0] = fmaf(a0.AC, WV.x, acc0[0]); acc0[1] = fmaf(a0.AC, WV.y, acc0[1]);  \
  acc0[2] = fmaf(a0.AC, WV.z, acc0[2]); acc0[3] = fmaf(a0.AC, WV.w, acc0[3]);  \
  acc1[0] = fmaf(a1.AC, WV.x, acc1[0]); acc1[1] = fmaf(a1.AC, WV.y, acc1[1]);  \
  acc1[2] = fmaf(a1.AC, WV.z, acc1[2]); acc1[3] = fmaf(a1.AC, WV.w, acc1[3]);
      GSTEP(x, w0) GSTEP(y, w1) GSTEP(z, w2) GSTEP(w, w3)
#undef GSTEP
    }
    float* ob = out + ((size_t)b * CH + d0) * NT + n0;
#pragma unroll
    for (int j = 0; j < 4; ++j) {
      float bv = bias[d0 + dd * 4 + j];
      float2 st;
      st.x = acc0[j] + bv;
      st.y = acc1[j] + bv;
      *(float2*)&ob[(size_t)(dd * 4 + j) * NT + 2 * nn] = st;
    }
  }
}

// ---------- per-channel sum / sumsq over (B,N) ----------
__global__ __launch_bounds__(256) void k_bnstats(const float* __restrict__ out,
                                                 float* __restrict__ stats) {
  const int bc = blockIdx.x;  // b*128 + c
  const int c = bc & 127;
  const float* p = out + (size_t)bc * NT;
  const int tid = threadIdx.x;
  float4 v = *(const float4*)&p[tid * 4];
  float s = v.x + v.y + v.z + v.w;
  float s2 = v.x * v.x + v.y * v.y + v.z * v.z + v.w * v.w;
#pragma unroll
  for (int o = 32; o > 0; o >>= 1) {
    s += __shfl_down(s, o);
    s2 += __shfl_down(s2, o);
  }
  __shared__ float ls[4], ls2[4];
  const int wid = tid >> 6, lane = tid & 63;
  if (lane == 0) { ls[wid] = s; ls2[wid] = s2; }
  __syncthreads();
  if (tid == 0) {
    atomicAdd(&stats[c], ls[0] + ls[1] + ls[2] + ls[3]);
    atomicAdd(&stats[CH + c], ls2[0] + ls2[1] + ls2[2] + ls2[3]);
  }
}

// ---------- BN + residual + ReLU, in place on d_out ----------
__global__ __launch_bounds__(256) void k_final(float* out,
                                               const float* __restrict__ x,
                                               const float* __restrict__ gamma,
                                               const float* __restrict__ beta,
                                               const float* __restrict__ stats) {
  const int i = blockIdx.x * 256 + threadIdx.x;  // float4 index
  const int c = (i >> 8) & 127;
  const float m = stats[c] * (1.0f / 32768.0f);
  const float var = stats[CH + c] * (1.0f / 32768.0f) - m * m;
  const float inv = rsqrtf(var + 1e-5f);
  const float g = gamma[c], be = beta[c];
  float4 ov = ((const float4*)out)[i];
  float4 xv = ((const float4*)x)[i];
  float4 r;
  r.x = fmaxf(g * (ov.x - m) * inv + be + xv.x, 0.f);
  r.y = fmaxf(g * (ov.y - m) * inv + be + xv.y, 0.f);
  r.z = fmaxf(g * (ov.z - m) * inv + be + xv.z, 0.f);
  r.w = fmaxf(g * (ov.w - m) * inv + be + xv.w, 0.f);
  ((float4*)out)[i] = r;
}

extern "C" void kernel_launch(void* const* d_in, const int* in_sizes, int n_in,
                              void* d_out, int out_size, void* d_ws, size_t ws_size,
                              hipStream_t stream) {
  const float* x = (const float*)d_in[0];
  const float* w = (const float*)d_in[1];
  const float* bias = (const float*)d_in[2];
  const float* gamma = (const float*)d_in[3];
  const float* beta = (const float*)d_in[4];
  // d_in[5] is k==9, baked in as KNN (compile-time top-k lists).
  float* out = (float*)d_out;
  char* wsb = (char*)d_ws;
  float* tok = (float*)(wsb);                 // 16 MB  (B,N,C) tokens
  float* sq = (float*)(wsb + 16777216);       // 128 KB per-token |t|^2
  int* topk = (int*)(wsb + 16908288);         // 1.125 MB (B,N,9) indices
  float* stats = (float*)(wsb + 18087936);    // 1 KB  BN sum/sumsq
  // total ws use ~18.1 MB

  k_sq<<<dim3(4, 32), 256, 0, stream>>>(x, sq, stats);          // also zeroes stats
  k_dist_topk<<<dim3(16, 32), 256, 0, stream>>>(x, sq, topk, tok);  // also emits tok
  k_agg_gemm<<<dim3(16, 32), 256, 0, stream>>>(tok, topk, w, bias, out);
  k_bnstats<<<4096, 256, 0, stream>>>(out, stats);
  k_final<<<4096, 256, 0, stream>>>(out, x, gamma, beta, stats);
}

// Round 5
// 350.632 us; speedup vs baseline: 1.5905x; 1.5905x over previous
//
#include <hip/hip_runtime.h>
#include <cfloat>

#define BB 32
#define CH 128
#define NT 1024
#define KNN 9

// ---------- sq[b][n] = sum_c x[b][c][n]^2 ; block(0,0) also zeroes BN stats ----------
__global__ __launch_bounds__(256) void k_sq(const float* __restrict__ x,
                                            float* __restrict__ sq,
                                            float* __restrict__ stats) {
  if (blockIdx.x == 0 && blockIdx.y == 0) stats[threadIdx.x] = 0.f;  // 256 floats
  const int b = blockIdx.y;
  const int n = blockIdx.x * 256 + threadIdx.x;
  const float* xb = x + (size_t)b * CH * NT + n;
  float s = 0.f;
#pragma unroll 8
  for (int c = 0; c < CH; ++c) {
    float v = xb[(size_t)c * NT];
    s = fmaf(v, v, s);
  }
  sq[b * NT + n] = s;
}

// ---------- transpose x (B,C,N) -> tok (B,N,C) ----------
__global__ __launch_bounds__(256) void k_transpose(const float* __restrict__ x,
                                                   float* __restrict__ tok) {
  __shared__ float t[32][33];
  const int b = blockIdx.z, c0 = blockIdx.y * 32, n0 = blockIdx.x * 32;
  const int tx = threadIdx.x, ty = threadIdx.y;  // 32 x 8
  const float* xb = x + (size_t)b * CH * NT;
#pragma unroll
  for (int k = 0; k < 4; ++k)
    t[ty + 8 * k][tx] = xb[(size_t)(c0 + ty + 8 * k) * NT + n0 + tx];
  __syncthreads();
  float* tb = tok + (size_t)b * NT * CH;
#pragma unroll
  for (int k = 0; k < 4; ++k)
    tb[(size_t)(n0 + ty + 8 * k) * CH + c0 + tx] = t[tx][ty + 8 * k];
}

// ---------- fused pairwise-dist + distributed per-row top-9 ----------
// Block: 256 threads, owns 64 rows; sweeps 8 column passes of 128 cols.
// Per-thread 4x8 microtile (cols tx*4+q and 64+tx*4+q keep B-reads 2-way).
// dist = sqrt(max(sq_i+sq_j-2*dot,0)); compare on sqrt'd value (reference tie
// structure). Top-9: 4 lanes per row keep private sorted top-9 over their
// column slice (ascending j => strict-less keeps smallest index on ties);
// merged once at the end with (val,idx) lexicographic compare == lax.top_k.
__global__ __launch_bounds__(256) void k_dist_topk(const float* __restrict__ x,
                                                   const float* __restrict__ sq,
                                                   int* __restrict__ topk) {
  __shared__ float As[32][64];    // c-chunk of this block's 64 rows
  __shared__ float Bs[32][128];   // c-chunk of current 128 cols
  __shared__ float d2s[64][68];   // half-tile (64 cols) dist; stride 68: 4-way max
  __shared__ float sqi[64];
  __shared__ float sqj[128];
  const int b = blockIdx.y;
  const int i0 = blockIdx.x * 64;
  const int tid = threadIdx.x;
  const int ty = tid >> 4, tx = tid & 15;  // 16x16 threads, 4x8 microtile
  const float* xb = x + (size_t)b * CH * NT;
  const float* sqb = sq + b * NT;

  if (tid < 64) sqi[tid] = sqb[i0 + tid];

  float val[KNN];
  int idx[KNN];
#pragma unroll
  for (int t = 0; t < KNN; ++t) { val[t] = FLT_MAX; idx[t] = 0x7fffffff; }

  for (int j0 = 0; j0 < NT; j0 += 128) {  // 8 passes
    if (tid < 128) sqj[tid] = sqb[j0 + tid];
    float acc[4][8];
#pragma unroll
    for (int r = 0; r < 4; ++r)
#pragma unroll
      for (int q = 0; q < 8; ++q) acc[r][q] = 0.f;

    for (int cc = 0; cc < CH; cc += 32) {
      __syncthreads();  // prev compute/scan done; sqj visible
      {  // stage As chunk: 512 float4, 2/thread, coalesced
#pragma unroll
        for (int k = 0; k < 2; ++k) {
          int e = tid + k * 256;
          int cl = e >> 4, cf = e & 15;
          *(float4*)&As[cl][cf * 4] =
              *(const float4*)(xb + (size_t)(cc + cl) * NT + i0 + cf * 4);
        }
        // stage Bs chunk: 1024 float4, 4/thread, coalesced
#pragma unroll
        for (int k = 0; k < 4; ++k) {
          int e = tid + k * 256;
          int cl = e >> 5, cf = e & 31;
          *(float4*)&Bs[cl][cf * 4] =
              *(const float4*)(xb + (size_t)(cc + cl) * NT + j0 + cf * 4);
        }
      }
      __syncthreads();
#pragma unroll
      for (int c = 0; c < 32; ++c) {
        float4 av = *(const float4*)&As[c][ty * 4];       // 4-addr broadcast
        float4 b0 = *(const float4*)&Bs[c][tx * 4];       // 2-way, free
        float4 b1 = *(const float4*)&Bs[c][64 + tx * 4];  // 2-way, free
#define FSTEP(R, AC)                                                        \
  acc[R][0] = fmaf(AC, b0.x, acc[R][0]);                                    \
  acc[R][1] = fmaf(AC, b0.y, acc[R][1]);                                    \
  acc[R][2] = fmaf(AC, b0.z, acc[R][2]);                                    \
  acc[R][3] = fmaf(AC, b0.w, acc[R][3]);                                    \
  acc[R][4] = fmaf(AC, b1.x, acc[R][4]);                                    \
  acc[R][5] = fmaf(AC, b1.y, acc[R][5]);                                    \
  acc[R][6] = fmaf(AC, b1.z, acc[R][6]);                                    \
  acc[R][7] = fmaf(AC, b1.w, acc[R][7]);
        FSTEP(0, av.x) FSTEP(1, av.y) FSTEP(2, av.z) FSTEP(3, av.w)
#undef FSTEP
      }
    }
    // two half-tiles: write dist, scan
#pragma unroll
    for (int h = 0; h < 2; ++h) {  // unrolled: acc index compile-time
#pragma unroll
      for (int r = 0; r < 4; ++r) {
        float si = sqi[ty * 4 + r];
        float4 dv;
        dv.x = sqrtf(fmaxf(si + sqj[h * 64 + tx * 4 + 0] - 2.f * acc[r][4 * h + 0], 0.f));
        dv.y = sqrtf(fmaxf(si + sqj[h * 64 + tx * 4 + 1] - 2.f * acc[r][4 * h + 1], 0.f));
        dv.z = sqrtf(fmaxf(si + sqj[h * 64 + tx * 4 + 2] - 2.f * acc[r][4 * h + 2], 0.f));
        dv.w = sqrtf(fmaxf(si + sqj[h * 64 + tx * 4 + 3] - 2.f * acc[r][4 * h + 3], 0.f));
        *(float4*)&d2s[ty * 4 + r][tx * 4] = dv;
      }
      __syncthreads();
      {  // scan: all 256 threads; lane (row, q) scans 16 cols ascending
        const int row = tid >> 2, q = tid & 3;
        const int jbase = j0 + h * 64 + q * 16;
        for (int jj = 0; jj < 16; ++jj) {
          float v = d2s[row][q * 16 + jj];
          if (v < val[KNN - 1]) {
            bool gt[KNN];
#pragma unroll
            for (int t = 0; t < KNN; ++t) gt[t] = (val[t] > v);
#pragma unroll
            for (int t = KNN - 1; t >= 1; --t)
              if (gt[t - 1]) { val[t] = val[t - 1]; idx[t] = idx[t - 1]; }
#pragma unroll
            for (int t = 0; t < KNN; ++t)
              if (gt[t] && (t == 0 || !gt[t - 1])) { val[t] = v; idx[t] = jbase + jj; }
          }
        }
      }
      __syncthreads();  // scan done before h=1 overwrite / next tile staging
    }
  }
  // merge the 4 per-row lists (lanes base..base+3) into q==0, lexicographic
  {
    const int base = (tid & 63) & 60;  // group base lane within wave
#pragma unroll
    for (int qq = 1; qq < 4; ++qq) {
#pragma unroll
      for (int t = 0; t < KNN; ++t) {
        float pv = __shfl(val[t], base + qq, 64);
        int pi = __shfl(idx[t], base + qq, 64);
        if ((tid & 3) == 0) {
          bool better = (pv < val[KNN - 1]) ||
                        (pv == val[KNN - 1] && pi < idx[KNN - 1]);
          if (better) {
            bool gt[KNN];
#pragma unroll
            for (int t2 = 0; t2 < KNN; ++t2)
              gt[t2] = (val[t2] > pv) || (val[t2] == pv && idx[t2] > pi);
#pragma unroll
            for (int t2 = KNN - 1; t2 >= 1; --t2)
              if (gt[t2 - 1]) { val[t2] = val[t2 - 1]; idx[t2] = idx[t2 - 1]; }
#pragma unroll
            for (int t2 = 0; t2 < KNN; ++t2)
              if (gt[t2] && (t2 == 0 || !gt[t2 - 1])) { val[t2] = pv; idx[t2] = pi; }
          }
        }
      }
    }
  }
  if ((tid & 3) == 0) {
    const int row = tid >> 2;
    int* tp = topk + ((size_t)b * NT + i0 + row) * KNN;
#pragma unroll
    for (int t = 0; t < KNN; ++t) tp[t] = idx[t];
  }
}

// ---------- gather 9 tokens, mean, GEMM with w^T, +bias, write (B,C,N) ----------
__global__ __launch_bounds__(256) void k_agg_gemm(const float* __restrict__ tok,
                                                  const int* __restrict__ topk,
                                                  const float* __restrict__ w,
                                                  const float* __restrict__ bias,
                                                  float* __restrict__ out) {
  __shared__ float agg_s[64][132];  // pad 4: float4-aligned rows, low conflicts
  __shared__ float w_s[CH][36];     // w chunk transposed [c][d'], pad to 36
  const int b = blockIdx.y;
  const int n0 = blockIdx.x * 64;
  const int tid = threadIdx.x;
  {  // gather+mean: 4 threads per row, 32 channels each
    const int row = tid >> 2, lp = tid & 3;
    const int* tp = topk + ((size_t)b * NT + n0 + row) * KNN;
    float a[32];
#pragma unroll
    for (int i = 0; i < 32; ++i) a[i] = 0.f;
    for (int t = 0; t < KNN; ++t) {
      const float* src = tok + ((size_t)b * NT + tp[t]) * CH + lp * 32;
#pragma unroll
      for (int i = 0; i < 8; ++i) {
        float4 v = *(const float4*)&src[4 * i];
        a[4 * i + 0] += v.x; a[4 * i + 1] += v.y;
        a[4 * i + 2] += v.z; a[4 * i + 3] += v.w;
      }
    }
    const float inv9 = 1.0f / 9.0f;
#pragma unroll
    for (int i = 0; i < 8; ++i) {
      float4 v;
      v.x = a[4 * i + 0] * inv9; v.y = a[4 * i + 1] * inv9;
      v.z = a[4 * i + 2] * inv9; v.w = a[4 * i + 3] * inv9;
      *(float4*)&agg_s[row][lp * 32 + 4 * i] = v;
    }
  }
  const int nn = tid >> 3, dd = tid & 7;  // rows 2nn,2nn+1; d' = dd*4..+3
  for (int d0 = 0; d0 < CH; d0 += 32) {
    __syncthreads();  // agg_s visible (1st iter); w_s reads done (later iters)
#pragma unroll
    for (int k = 0; k < 16; ++k) {
      int e = tid + k * 256;
      int c = e & 127, dl = e >> 7;
      w_s[c][dl] = w[(size_t)(d0 + dl) * CH + c];
    }
    __syncthreads();
    float acc0[4] = {0.f, 0.f, 0.f, 0.f};
    float acc1[4] = {0.f, 0.f, 0.f, 0.f};
    for (int c4 = 0; c4 < 32; ++c4) {
      float4 a0 = *(const float4*)&agg_s[2 * nn][4 * c4];
      float4 a1 = *(const float4*)&agg_s[2 * nn + 1][4 * c4];
      float4 w0 = *(const float4*)&w_s[4 * c4 + 0][dd * 4];
      float4 w1 = *(const float4*)&w_s[4 * c4 + 1][dd * 4];
      float4 w2 = *(const float4*)&w_s[4 * c4 + 2][dd * 4];
      float4 w3 = *(const float4*)&w_s[4 * c4 + 3][dd * 4];
#define GSTEP(AC, WV)                                                          \
  acc0[0] = fmaf(a0.AC, WV.x, acc0[0]); acc0[1] = fmaf(a0.AC, WV.y, acc0[1]);  \
  acc0[2] = fmaf(a0.AC, WV.z, acc0[2]); acc0[3] = fmaf(a0.AC, WV.w, acc0[3]);  \
  acc1[0] = fmaf(a1.AC, WV.x, acc1[0]); acc1[1] = fmaf(a1.AC, WV.y, acc1[1]);  \
  acc1[2] = fmaf(a1.AC, WV.z, acc1[2]); acc1[3] = fmaf(a1.AC, WV.w, acc1[3]);
      GSTEP(x, w0) GSTEP(y, w1) GSTEP(z, w2) GSTEP(w, w3)
#undef GSTEP
    }
    float* ob = out + ((size_t)b * CH + d0) * NT + n0;
#pragma unroll
    for (int j = 0; j < 4; ++j) {
      float bv = bias[d0 + dd * 4 + j];
      float2 st;
      st.x = acc0[j] + bv;
      st.y = acc1[j] + bv;
      *(float2*)&ob[(size_t)(dd * 4 + j) * NT + 2 * nn] = st;
    }
  }
}

// ---------- per-channel sum / sumsq over (B,N) ----------
__global__ __launch_bounds__(256) void k_bnstats(const float* __restrict__ out,
                                                 float* __restrict__ stats) {
  const int bc = blockIdx.x;  // b*128 + c
  const int c = bc & 127;
  const float* p = out + (size_t)bc * NT;
  const int tid = threadIdx.x;
  float4 v = *(const float4*)&p[tid * 4];
  float s = v.x + v.y + v.z + v.w;
  float s2 = v.x * v.x + v.y * v.y + v.z * v.z + v.w * v.w;
#pragma unroll
  for (int o = 32; o > 0; o >>= 1) {
    s += __shfl_down(s, o);
    s2 += __shfl_down(s2, o);
  }
  __shared__ float ls[4], ls2[4];
  const int wid = tid >> 6, lane = tid & 63;
  if (lane == 0) { ls[wid] = s; ls2[wid] = s2; }
  __syncthreads();
  if (tid == 0) {
    atomicAdd(&stats[c], ls[0] + ls[1] + ls[2] + ls[3]);
    atomicAdd(&stats[CH + c], ls2[0] + ls2[1] + ls2[2] + ls2[3]);
  }
}

// ---------- BN + residual + ReLU, in place on d_out ----------
__global__ __launch_bounds__(256) void k_final(float* out,
                                               const float* __restrict__ x,
                                               const float* __restrict__ gamma,
                                               const float* __restrict__ beta,
                                               const float* __restrict__ stats) {
  const int i = blockIdx.x * 256 + threadIdx.x;  // float4 index
  const int c = (i >> 8) & 127;
  const float m = stats[c] * (1.0f / 32768.0f);
  const float var = stats[CH + c] * (1.0f / 32768.0f) - m * m;
  const float inv = rsqrtf(var + 1e-5f);
  const float g = gamma[c], be = beta[c];
  float4 ov = ((const float4*)out)[i];
  float4 xv = ((const float4*)x)[i];
  float4 r;
  r.x = fmaxf(g * (ov.x - m) * inv + be + xv.x, 0.f);
  r.y = fmaxf(g * (ov.y - m) * inv + be + xv.y, 0.f);
  r.z = fmaxf(g * (ov.z - m) * inv + be + xv.z, 0.f);
  r.w = fmaxf(g * (ov.w - m) * inv + be + xv.w, 0.f);
  ((float4*)out)[i] = r;
}

extern "C" void kernel_launch(void* const* d_in, const int* in_sizes, int n_in,
                              void* d_out, int out_size, void* d_ws, size_t ws_size,
                              hipStream_t stream) {
  const float* x = (const float*)d_in[0];
  const float* w = (const float*)d_in[1];
  const float* bias = (const float*)d_in[2];
  const float* gamma = (const float*)d_in[3];
  const float* beta = (const float*)d_in[4];
  // d_in[5] is k==9, baked in as KNN (compile-time top-k lists).
  float* out = (float*)d_out;
  char* wsb = (char*)d_ws;
  float* tok = (float*)(wsb);                 // 16 MB  (B,N,C) tokens
  float* sq = (float*)(wsb + 16777216);       // 128 KB per-token |t|^2
  int* topk = (int*)(wsb + 16908288);         // 1.125 MB (B,N,9) indices
  float* stats = (float*)(wsb + 18087936);    // 1 KB  BN sum/sumsq
  // total ws use ~18.1 MB

  k_sq<<<dim3(4, 32), 256, 0, stream>>>(x, sq, stats);  // also zeroes stats
  k_transpose<<<dim3(32, 4, 32), dim3(32, 8), 0, stream>>>(x, tok);
  k_dist_topk<<<dim3(16, 32), 256, 0, stream>>>(x, sq, topk);
  k_agg_gemm<<<dim3(16, 32), 256, 0, stream>>>(tok, topk, w, bias, out);
  k_bnstats<<<4096, 256, 0, stream>>>(out, stats);
  k_final<<<4096, 256, 0, stream>>>(out, x, gamma, beta, stats);
}

// Round 9
// 350.482 us; speedup vs baseline: 1.5912x; 1.0004x over previous
//
#include <hip/hip_runtime.h>
#include <cfloat>

#define BB 32
#define CH 128
#define NT 1024
#define KNN 9
#define NCAND 48  // 4 lanes/row x top-12 each

typedef unsigned int u32;
typedef unsigned short u16;
using bf16x8 = __attribute__((ext_vector_type(8))) short;
using f32x4 = __attribute__((ext_vector_type(4))) float;

// fp32 -> bf16 round-to-nearest-even (self-contained)
__device__ __forceinline__ u16 f2bf(float f) {
  u32 u = __float_as_uint(f);
  u32 r = (u + 0x7FFFu + ((u >> 16) & 1u)) >> 16;
  return (u16)r;
}

// ---------- sq[b][n] = sum_c x[b][c][n]^2 ; block(0,0) also zeroes BN stats ----------
__global__ __launch_bounds__(256) void k_sq(const float* __restrict__ x,
                                            float* __restrict__ sq,
                                            float* __restrict__ stats) {
  if (blockIdx.x == 0 && blockIdx.y == 0) stats[threadIdx.x] = 0.f;
  const int b = blockIdx.y;
  const int n = blockIdx.x * 256 + threadIdx.x;
  const float* xb = x + (size_t)b * CH * NT + n;
  float s = 0.f;
#pragma unroll 8
  for (int c = 0; c < CH; ++c) {
    float v = xb[(size_t)c * NT];
    s = fmaf(v, v, s);
  }
  sq[b * NT + n] = s;
}

// ---------- transpose x (B,C,N) -> tok (B,N,C) fp32  AND  xh (B,N,C) bf16 ----------
__global__ __launch_bounds__(256) void k_transpose(const float* __restrict__ x,
                                                   float* __restrict__ tok,
                                                   u16* __restrict__ xh) {
  __shared__ float t[32][33];
  const int b = blockIdx.z, c0 = blockIdx.y * 32, n0 = blockIdx.x * 32;
  const int tx = threadIdx.x, ty = threadIdx.y;  // 32 x 8
  const float* xb = x + (size_t)b * CH * NT;
#pragma unroll
  for (int k = 0; k < 4; ++k)
    t[ty + 8 * k][tx] = xb[(size_t)(c0 + ty + 8 * k) * NT + n0 + tx];
  __syncthreads();
  float* tb = tok + (size_t)b * NT * CH;
  u16* hb = xh + (size_t)b * NT * CH;
#pragma unroll
  for (int k = 0; k < 4; ++k) {
    float v = t[tx][ty + 8 * k];
    tb[(size_t)(n0 + ty + 8 * k) * CH + c0 + tx] = v;
    hb[(size_t)(n0 + ty + 8 * k) * CH + c0 + tx] = f2bf(v);
  }
}

// ---------- MFMA bf16 prefilter: approx d2 + per-lane top-12 candidates ----------
// Block 256 thr (4 waves), owns 64 rows; 16 passes of 64 cols. Wave w computes
// rows 16w..16w+15 via mfma_f32_16x16x32_bf16 (A-frags from global xh once,
// kept in regs; B-tile staged in LDS, XOR-swizzled byte^=((col&7)<<4), T2).
// d2_approx = sq_i + sq_j - 2*dot_bf16, clamped >=0; packed key =
// (f32bits & ~0x3FF) | j (order-preserving for d2>=0; ~0.05 total noise).
// 4 lanes/row each keep branchless sorted top-12 over their col slice
// ((j>>4)&3 == q). Margin analysis: losing a true-top-9 needs >=4 noise jumps
// over multi-sigma gaps -> P~0. Exact selection restored by k_rerank.
__global__ __launch_bounds__(256) void k_distf(const u16* __restrict__ xh,
                                               const float* __restrict__ sq,
                                               int* __restrict__ cand) {
  __shared__ float4 Bh4[1024];     // 64 cols x 128 k bf16, swizzled (16 KB)
  __shared__ float d2sT[64][68];   // [col][row], stride 68: b128-aligned rows
  __shared__ float sqi_s[64];
  __shared__ float sqj_s[64];
  const int b = blockIdx.y;
  const int i0 = blockIdx.x * 64;
  const int tid = threadIdx.x;
  const int l = tid & 63, w = tid >> 6;    // lane, wave
  const int l15 = l & 15, lo = l >> 4;     // frag row/col sel, k-octet
  const u16* xb = xh + (size_t)b * NT * CH;  // token-major [N][C]
  const float* sqb = sq + b * NT;

  if (tid < 64) sqi_s[tid] = sqb[i0 + tid];

  // A-fragments: rows i0+16w+l15, k = ks*32 + lo*8 .. +8 (16B aligned, global)
  bf16x8 af[4];
#pragma unroll
  for (int ks = 0; ks < 4; ++ks)
    af[ks] = *(const bf16x8*)(xb + (size_t)(i0 + 16 * w + l15) * CH + ks * 32 + lo * 8);

  u32 kv[12];
#pragma unroll
  for (int t = 0; t < 12; ++t) kv[t] = 0xFFFFFFFFu;

  for (int p = 0; p < 16; ++p) {
    const int j0 = p * 64;
    __syncthreads();  // prev scan done: Bh/d2sT free
    // stage B tile: 64 cols x 128 k bf16, coalesced 16B reads, swizzled writes
#pragma unroll
    for (int k = 0; k < 4; ++k) {
      int e = tid + k * 256;        // 16B-unit index: col = e>>4, ko = e&15
      int col = e >> 4, ko = e & 15;
      u32 byteoff = (u32)(col * 256 + ko * 16) ^ (u32)((col & 7) << 4);
      Bh4[byteoff >> 4] = *(const float4*)(xb + (size_t)(j0 + col) * CH + ko * 8);
    }
    if (tid < 64) sqj_s[tid] = sqb[j0 + tid];
    __syncthreads();
    // MFMA: 4 col-subtiles x 4 K-steps
    f32x4 acc[4];
#pragma unroll
    for (int ct = 0; ct < 4; ++ct) {
      acc[ct] = (f32x4){0.f, 0.f, 0.f, 0.f};
#pragma unroll
      for (int ks = 0; ks < 4; ++ks) {
        int col = ct * 16 + l15;
        int ko = ks * 4 + lo;
        u32 byteoff = (u32)(col * 256 + ko * 16) ^ (u32)((col & 7) << 4);
        bf16x8 bfr = *(const bf16x8*)((const char*)Bh4 + byteoff);
        acc[ct] = __builtin_amdgcn_mfma_f32_16x16x32_bf16(af[ks], bfr, acc[ct], 0, 0, 0);
      }
    }
    // assemble d2 -> d2sT[col][row] (C/D: col=lane&15, row=lo*4+reg; verified)
    float4 sv = *(const float4*)&sqi_s[16 * w + lo * 4];
#pragma unroll
    for (int ct = 0; ct < 4; ++ct) {
      int col = ct * 16 + l15;
      float sj = sqj_s[col];
      float4 dv;
      dv.x = fmaxf(sv.x + sj - 2.f * acc[ct][0], 0.f);
      dv.y = fmaxf(sv.y + sj - 2.f * acc[ct][1], 0.f);
      dv.z = fmaxf(sv.z + sj - 2.f * acc[ct][2], 0.f);
      dv.w = fmaxf(sv.w + sj - 2.f * acc[ct][3], 0.f);
      *(float4*)&d2sT[col][16 * w + lo * 4] = dv;
    }
    __syncthreads();
    // scan: lane (row=tid>>2, q=tid&3) scans 16 cols; packed-key top-12
    {
      const int row = tid >> 2, q = tid & 3;
#pragma unroll 4
      for (int jj = 0; jj < 16; ++jj) {
        int col = q * 16 + jj;
        float d = d2sT[col][row];
        u32 key = (__float_as_uint(d) & 0xFFFFFC00u) | (u32)(j0 + col);
        if (key < kv[11]) {  // branchless bubble-through insert (12 min+max)
          u32 c = key;
#pragma unroll
          for (int t = 0; t < 12; ++t) {
            u32 m = kv[t];
            kv[t] = m < c ? m : c;
            c = m < c ? c : m;
          }
        }
      }
    }
  }
  // emit candidates: 4 lanes/row x 12 (disjoint col slices -> no dupes)
  {
    const int row = tid >> 2, q = tid & 3;
    int* cp = cand + ((size_t)b * NT + i0 + row) * NCAND + q * 12;
#pragma unroll
    for (int t = 0; t < 12; ++t) cp[t] = (int)(kv[t] & 1023u);
  }
}

// ---------- exact fp32 rerank: 48 cands -> top-9 by (dist, idx), = lax.top_k ----------
// One wave per row; lane j<48 computes exact dist to cand j with the SAME
// ascending-c fmaf chain as the round-5 kernel (bit-identical values), then
// 9 lexicographic min-extractions via shfl_xor butterfly.
__global__ __launch_bounds__(256) void k_rerank(const float* __restrict__ tok,
                                                const float* __restrict__ sq,
                                                const int* __restrict__ cand,
                                                int* __restrict__ topk) {
  const int g = blockIdx.x * 4 + (threadIdx.x >> 6);  // global row
  const int lane = threadIdx.x & 63;
  const int b = g >> 10, n = g & 1023;
  const float* trow = tok + (size_t)(b * NT + n) * CH;
  float v;
  int ci;
  if (lane < NCAND) {
    ci = cand[(size_t)g * NCAND + lane];
    const float* tc = tok + (size_t)(b * NT + ci) * CH;
    float acc = 0.f;
#pragma unroll
    for (int k = 0; k < 32; ++k) {
      float4 a = *(const float4*)&trow[4 * k];  // broadcast (same addr all lanes)
      float4 c4 = *(const float4*)&tc[4 * k];
      acc = fmaf(a.x, c4.x, acc);
      acc = fmaf(a.y, c4.y, acc);
      acc = fmaf(a.z, c4.z, acc);
      acc = fmaf(a.w, c4.w, acc);
    }
    float d2 = sq[b * NT + n] + sq[b * NT + ci] - 2.f * acc;
    v = sqrtf(fmaxf(d2, 0.f));
  } else {
    v = FLT_MAX;
    ci = 0x7fffffff;
  }
  int out[KNN];
#pragma unroll
  for (int t = 0; t < KNN; ++t) {
    float mv = v;
    int mi = ci;
#pragma unroll
    for (int off = 32; off > 0; off >>= 1) {
      float ov = __shfl_xor(mv, off, 64);
      int oi = __shfl_xor(mi, off, 64);
      bool better = (ov < mv) || (ov == mv && oi < mi);
      mv = better ? ov : mv;
      mi = better ? oi : mi;
    }
    out[t] = mi;
    if (ci == mi) { v = FLT_MAX; ci = 0x7fffffff; }  // retire winner (idx unique)
  }
  if (lane == 0) {
    int* tp = topk + (size_t)g * KNN;
#pragma unroll
    for (int t = 0; t < KNN; ++t) tp[t] = out[t];
  }
}

// ---------- gather 9 tokens, mean, GEMM with w^T, +bias, write (B,C,N) ----------
__global__ __launch_bounds__(256) void k_agg_gemm(const float* __restrict__ tok,
                                                  const int* __restrict__ topk,
                                                  const float* __restrict__ w,
                                                  const float* __restrict__ bias,
                                                  float* __restrict__ out) {
  __shared__ float agg_s[64][132];
  __shared__ float w_s[CH][36];
  const int b = blockIdx.y;
  const int n0 = blockIdx.x * 64;
  const int tid = threadIdx.x;
  {
    const int row = tid >> 2, lp = tid & 3;
    const int* tp = topk + ((size_t)b * NT + n0 + row) * KNN;
    float a[32];
#pragma unroll
    for (int i = 0; i < 32; ++i) a[i] = 0.f;
    for (int t = 0; t < KNN; ++t) {
      const float* src = tok + ((size_t)b * NT + tp[t]) * CH + lp * 32;
#pragma unroll
      for (int i = 0; i < 8; ++i) {
        float4 v = *(const float4*)&src[4 * i];
        a[4 * i + 0] += v.x; a[4 * i + 1] += v.y;
        a[4 * i + 2] += v.z; a[4 * i + 3] += v.w;
      }
    }
    const float inv9 = 1.0f / 9.0f;
#pragma unroll
    for (int i = 0; i < 8; ++i) {
      float4 v;
      v.x = a[4 * i + 0] * inv9; v.y = a[4 * i + 1] * inv9;
      v.z = a[4 * i + 2] * inv9; v.w = a[4 * i + 3] * inv9;
      *(float4*)&agg_s[row][lp * 32 + 4 * i] = v;
    }
  }
  const int nn = tid >> 3, dd = tid & 7;
  for (int d0 = 0; d0 < CH; d0 += 32) {
    __syncthreads();
#pragma unroll
    for (int k = 0; k < 16; ++k) {
      int e = tid + k * 256;
      int c = e & 127, dl = e >> 7;
      w_s[c][dl] = w[(size_t)(d0 + dl) * CH + c];
    }
    __syncthreads();
    float acc0[4] = {0.f, 0.f, 0.f, 0.f};
    float acc1[4] = {0.f, 0.f, 0.f, 0.f};
    for (int c4 = 0; c4 < 32; ++c4) {
      float4 a0 = *(const float4*)&agg_s[2 * nn][4 * c4];
      float4 a1 = *(const float4*)&agg_s[2 * nn + 1][4 * c4];
      float4 w0 = *(const float4*)&w_s[4 * c4 + 0][dd * 4];
      float4 w1 = *(const float4*)&w_s[4 * c4 + 1][dd * 4];
      float4 w2 = *(const float4*)&w_s[4 * c4 + 2][dd * 4];
      float4 w3 = *(const float4*)&w_s[4 * c4 + 3][dd * 4];
#define GSTEP(AC, WV)                                                          \
  acc0[0] = fmaf(a0.AC, WV.x, acc0[0]); acc0[1] = fmaf(a0.AC, WV.y, acc0[1]);  \
  acc0[2] = fmaf(a0.AC, WV.z, acc0[2]); acc0[3] = fmaf(a0.AC, WV.w, acc0[3]);  \
  acc1[0] = fmaf(a1.AC, WV.x, acc1[0]); acc1[1] = fmaf(a1.AC, WV.y, acc1[1]);  \
  acc1[2] = fmaf(a1.AC, WV.z, acc1[2]); acc1[3] = fmaf(a1.AC, WV.w, acc1[3]);
      GSTEP(x, w0) GSTEP(y, w1) GSTEP(z, w2) GSTEP(w, w3)
#undef GSTEP
    }
    float* ob = out + ((size_t)b * CH + d0) * NT + n0;
#pragma unroll
    for (int j = 0; j < 4; ++j) {
      float bv = bias[d0 + dd * 4 + j];
      float2 st;
      st.x = acc0[j] + bv;
      st.y = acc1[j] + bv;
      *(float2*)&ob[(size_t)(dd * 4 + j) * NT + 2 * nn] = st;
    }
  }
}

// ---------- per-channel sum / sumsq over (B,N) ----------
__global__ __launch_bounds__(256) void k_bnstats(const float* __restrict__ out,
                                                 float* __restrict__ stats) {
  const int bc = blockIdx.x;
  const int c = bc & 127;
  const float* p = out + (size_t)bc * NT;
  const int tid = threadIdx.x;
  float4 v = *(const float4*)&p[tid * 4];
  float s = v.x + v.y + v.z + v.w;
  float s2 = v.x * v.x + v.y * v.y + v.z * v.z + v.w * v.w;
#pragma unroll
  for (int o = 32; o > 0; o >>= 1) {
    s += __shfl_down(s, o);
    s2 += __shfl_down(s2, o);
  }
  __shared__ float ls[4], ls2[4];
  const int wid = tid >> 6, lane = tid & 63;
  if (lane == 0) { ls[wid] = s; ls2[wid] = s2; }
  __syncthreads();
  if (tid == 0) {
    atomicAdd(&stats[c], ls[0] + ls[1] + ls[2] + ls[3]);
    atomicAdd(&stats[CH + c], ls2[0] + ls2[1] + ls2[2] + ls2[3]);
  }
}

// ---------- BN + residual + ReLU, in place on d_out ----------
__global__ __launch_bounds__(256) void k_final(float* out,
                                               const float* __restrict__ x,
                                               const float* __restrict__ gamma,
                                               const float* __restrict__ beta,
                                               const float* __restrict__ stats) {
  const int i = blockIdx.x * 256 + threadIdx.x;
  const int c = (i >> 8) & 127;
  const float m = stats[c] * (1.0f / 32768.0f);
  const float var = stats[CH + c] * (1.0f / 32768.0f) - m * m;
  const float inv = rsqrtf(var + 1e-5f);
  const float g = gamma[c], be = beta[c];
  float4 ov = ((const float4*)out)[i];
  float4 xv = ((const float4*)x)[i];
  float4 r;
  r.x = fmaxf(g * (ov.x - m) * inv + be + xv.x, 0.f);
  r.y = fmaxf(g * (ov.y - m) * inv + be + xv.y, 0.f);
  r.z = fmaxf(g * (ov.z - m) * inv + be + xv.z, 0.f);
  r.w = fmaxf(g * (ov.w - m) * inv + be + xv.w, 0.f);
  ((float4*)out)[i] = r;
}

extern "C" void kernel_launch(void* const* d_in, const int* in_sizes, int n_in,
                              void* d_out, int out_size, void* d_ws, size_t ws_size,
                              hipStream_t stream) {
  const float* x = (const float*)d_in[0];
  const float* w = (const float*)d_in[1];
  const float* bias = (const float*)d_in[2];
  const float* gamma = (const float*)d_in[3];
  const float* beta = (const float*)d_in[4];
  float* out = (float*)d_out;
  char* wsb = (char*)d_ws;
  float* tok = (float*)(wsb);                  // 16 MB   (B,N,C) fp32 tokens
  u16* xh = (u16*)(wsb + 16777216);            // 8 MB    (B,N,C) bf16 tokens
  float* sq = (float*)(wsb + 25165824);        // 128 KB  |t|^2
  int* cand = (int*)(wsb + 25296896);          // 6.29 MB (B,N,48) prefilter cands
  int* topk = (int*)(wsb + 31588352);          // 1.125 MB (B,N,9) exact indices
  float* stats = (float*)(wsb + 32767744);     // 1 KB    BN sum/sumsq
  // total ws use ~32.8 MB

  k_sq<<<dim3(4, 32), 256, 0, stream>>>(x, sq, stats);  // also zeroes stats
  k_transpose<<<dim3(32, 4, 32), dim3(32, 8), 0, stream>>>(x, tok, xh);
  k_distf<<<dim3(16, 32), 256, 0, stream>>>(xh, sq, cand);
  k_rerank<<<8192, 256, 0, stream>>>(tok, sq, cand, topk);
  k_agg_gemm<<<dim3(16, 32), 256, 0, stream>>>(tok, topk, w, bias, out);
  k_bnstats<<<4096, 256, 0, stream>>>(out, stats);
  k_final<<<4096, 256, 0, stream>>>(out, x, gamma, beta, stats);
}